// Round 6
// baseline (459.532 us; speedup 1.0000x reference)
//
#include <hip/hip_runtime.h>
#include <hip/hip_fp16.h>

#define NEG_SLOPE 0.2f

// ---------------------------------------------------------------------------
// float<->ordered-uint encoding for atomicMax on floats
// ---------------------------------------------------------------------------
__device__ inline unsigned enc_max(float f) {
    unsigned b = __float_as_uint(f);
    return (b & 0x80000000u) ? ~b : (b | 0x80000000u);
}
__device__ inline float dec_max(unsigned k) {
    return (k & 0x80000000u) ? __uint_as_float(k ^ 0x80000000u)
                             : __uint_as_float(~k);
}

// ---------------------------------------------------------------------------
// GEMM + attention projections.
//   H16[r,:] = fp16(X[r,:] @ W); AL[r] = (als_h0, als_h1, ald_h0, ald_h1)
// W staged in LDS as fp16 half8 entries: Wh[kq][l] = rows 4kq..4kq+3 of cols
// {2l, 2l+1} -> ONE ds_read_b128 per kq. x rows staged fp32 per-wave (xb),
// read as same-address b128 broadcasts. Accumulation fp32 (v_fma_mix).
// LDS = 32 KB (Wh) + 16 KB (xb) = 48 KB -> 3 blocks/CU -> 6 waves/SIMD.
// Also folds global max of als per head (softmax shift ub) via 2 atomics.
// ---------------------------------------------------------------------------
__device__ inline void row_out(int r, int N, int lane, float A0, float A1,
                               float as0, float as1, float ad0, float ad1,
                               __half* __restrict__ H16, float* __restrict__ AL,
                               float& rmax)
{
    if (r >= N) return;
    ((__half2*)H16)[(size_t)r * 64 + lane] = __float22half2_rn(make_float2(A0, A1));
    float ps = A0 * as0 + A1 * as1;
    float pd = A0 * ad0 + A1 * ad1;
#pragma unroll
    for (int off = 16; off > 0; off >>= 1) {   // reduce within each 32-lane head
        ps += __shfl_xor(ps, off, 64);
        pd += __shfl_xor(pd, off, 64);
    }
    rmax = fmaxf(rmax, ps);                    // valid at lanes 0 (h0) / 32 (h1)
    if (lane == 0)       { AL[(size_t)r * 4 + 0] = ps; AL[(size_t)r * 4 + 2] = pd; }
    else if (lane == 32) { AL[(size_t)r * 4 + 1] = ps; AL[(size_t)r * 4 + 3] = pd; }
}

__global__ __launch_bounds__(512) void gemm_al_kernel(
    const float* __restrict__ X, const float* __restrict__ W,
    const float* __restrict__ asrc, const float* __restrict__ adst,
    __half* __restrict__ H16, float* __restrict__ AL,
    unsigned* __restrict__ ubp, int N)
{
    __shared__ alignas(16) __half Wh[32 * 64 * 8];   // 32 KiB
    __shared__ float xb[8][4][128];                  // 16 KiB

    const int t = threadIdx.x, lane = t & 63, wave = t >> 6;

    {   // stage W -> fp16 (one-time)
        const float2* Wg = (const float2*)W;   // [k][64 channel-pairs]
#pragma unroll
        for (int idx = t; idx < 2048; idx += 512) {
            const int kq = idx >> 6, l = idx & 63;
            __half2* dst = (__half2*)&Wh[(size_t)(kq * 64 + l) * 8];
#pragma unroll
            for (int i = 0; i < 4; i++) {
                float2 w = Wg[(4 * kq + i) * 64 + l];
                dst[i] = __float22half2_rn(w);
            }
        }
    }
    __syncthreads();

    const float as0 = asrc[2 * lane], as1 = asrc[2 * lane + 1];
    const float ad0 = adst[2 * lane], ad1 = adst[2 * lane + 1];

    const int i0 = lane, i1 = lane + 64;       // float4 slots within 4x128 chunk
    const int r0i = i0 >> 5, k0i = i0 & 31;
    const int r1i = i1 >> 5, k1i = i1 & 31;
    const int rowbase = (blockIdx.x * 8 + wave) * 16;
    float rmax = -__builtin_inff();

    // prefetch chunk 0
    float4 pA = make_float4(0, 0, 0, 0), pB = make_float4(0, 0, 0, 0);
    if (rowbase + r0i < N) pA = ((const float4*)(X + (size_t)(rowbase + r0i) * 128))[k0i];
    if (rowbase + r1i < N) pB = ((const float4*)(X + (size_t)(rowbase + r1i) * 128))[k1i];

    for (int c = 0; c < 4; c++) {
        const int rbase = rowbase + c * 4;
        if (rbase >= N) break;

        ((float4*)xb[wave][r0i])[k0i] = pA;
        ((float4*)xb[wave][r1i])[k1i] = pB;

        if (c < 3) {
            const int nb = rowbase + (c + 1) * 4;
            pA = make_float4(0, 0, 0, 0); pB = make_float4(0, 0, 0, 0);
            if (nb + r0i < N) pA = ((const float4*)(X + (size_t)(nb + r0i) * 128))[k0i];
            if (nb + r1i < N) pB = ((const float4*)(X + (size_t)(nb + r1i) * 128))[k1i];
        }

        float2 acc[4];
#pragma unroll
        for (int r = 0; r < 4; r++) acc[r] = make_float2(0.f, 0.f);

#pragma unroll 4
        for (int kq = 0; kq < 32; kq++) {
            const uint4 wraw = ((const uint4*)Wh)[kq * 64 + lane];   // b128
            const __half2* wh = (const __half2*)&wraw;
            const float2 w0 = __half22float2(wh[0]);   // row 4kq+0: (2l, 2l+1)
            const float2 w1 = __half22float2(wh[1]);
            const float2 w2 = __half22float2(wh[2]);
            const float2 w3 = __half22float2(wh[3]);
#pragma unroll
            for (int r = 0; r < 4; r++) {
                const float4 xr = ((const float4*)xb[wave][r])[kq];  // broadcast
                acc[r].x = fmaf(xr.x, w0.x, acc[r].x);
                acc[r].y = fmaf(xr.x, w0.y, acc[r].y);
                acc[r].x = fmaf(xr.y, w1.x, acc[r].x);
                acc[r].y = fmaf(xr.y, w1.y, acc[r].y);
                acc[r].x = fmaf(xr.z, w2.x, acc[r].x);
                acc[r].y = fmaf(xr.z, w2.y, acc[r].y);
                acc[r].x = fmaf(xr.w, w3.x, acc[r].x);
                acc[r].y = fmaf(xr.w, w3.y, acc[r].y);
            }
        }
#pragma unroll
        for (int r = 0; r < 4; r++)
            row_out(rbase + r, N, lane, acc[r].x, acc[r].y,
                    as0, as1, ad0, ad1, H16, AL, rmax);
    }

    // fold: block-level max of als per head -> 2 atomics (reuse xb as scratch)
    __syncthreads();
    float* red = (float*)xb;
    if (lane == 0)       red[wave * 2 + 0] = rmax;
    else if (lane == 32) red[wave * 2 + 1] = rmax;
    __syncthreads();
    if (t < 2) {
        float m = red[t];
#pragma unroll
        for (int i = 1; i < 8; i++) m = fmaxf(m, red[2 * i + t]);
        atomicMax(&ubp[t], enc_max(m));
    }
}

// ---------------------------------------------------------------------------
// Plain per-dst CSR build (count -> scan -> sliced scatter). Self-loops added.
// ---------------------------------------------------------------------------
__global__ void count_kernel(const int* __restrict__ edst, int* __restrict__ cnt,
                             int E, int N)
{
    int i = blockIdx.x * 256 + threadIdx.x;
    if (i < E)            atomicAdd(&cnt[edst[i]], 1);
    else if (i < E + N)   atomicAdd(&cnt[i - E], 1);   // self loop
}

__global__ void scan_local_kernel(const int* __restrict__ in, int* __restrict__ out,
                                  int* __restrict__ bsum, int n)
{
    __shared__ int sm[1024];
    const int t = threadIdx.x;
    const int i = blockIdx.x * 1024 + t;
    int v = (i < n) ? in[i] : 0;
    sm[t] = v;
    __syncthreads();
    for (int off = 1; off < 1024; off <<= 1) {
        int x = (t >= off) ? sm[t - off] : 0;
        __syncthreads();
        sm[t] += x;
        __syncthreads();
    }
    if (i < n) out[i] = sm[t];
    if (t == 1023) bsum[blockIdx.x] = sm[t];
}

__global__ void scan_excl_single_kernel(int* __restrict__ a, int B)
{
    __shared__ int sm[1024];
    const int t = threadIdx.x;
    int v = (t < B) ? a[t] : 0;
    sm[t] = v;
    __syncthreads();
    for (int off = 1; off < 1024; off <<= 1) {
        int x = (t >= off) ? sm[t - off] : 0;
        __syncthreads();
        sm[t] += x;
        __syncthreads();
    }
    if (t < B) a[t] = sm[t] - v;   // exclusive
}

__global__ void finalize_csr_kernel(const int* __restrict__ incl,
                                    const int* __restrict__ cnt,
                                    const int* __restrict__ bexcl,
                                    int* __restrict__ dstptr, int* __restrict__ cursor,
                                    int N, int Etot)
{
    const int i = blockIdx.x * 1024 + threadIdx.x;
    if (i < N) {
        int v = incl[i] + bexcl[i >> 10] - cnt[i];
        dstptr[i] = v;
        cursor[i] = v;
    }
    if (i == N) dstptr[N] = Etot;
}

// Sliced scatter: blocks with blockIdx%8==s handle dst slice s (-> one XCD by
// round-robin dispatch), so each ssrc cache line is written by one XCD only.
__global__ void scatter_kernel(const int* __restrict__ esrc, const int* __restrict__ edst,
                               int* __restrict__ cursor, int* __restrict__ ssrc,
                               int E, int N, int sliceN, int bps)
{
    const int slice = blockIdx.x & 7;
    const int dlo = slice * sliceN;
    const int dhi = min(N, dlo + sliceN);
    const int Etot = E + N;
    for (int i = (blockIdx.x >> 3) * 256 + (int)threadIdx.x; i < Etot; i += bps * 256) {
        int s, d;
        if (i < E) { s = esrc[i]; d = edst[i]; }
        else       { s = d = i - E; }
        if (d >= dlo && d < dhi) {
            int pos = atomicAdd(&cursor[d], 1);
            ssrc[pos] = s;
        }
    }
}

// ---------------------------------------------------------------------------
// Aggregation, shifted softmax. TWO nodes per wave: lanes 0-31 node A,
// lanes 32-63 node B; lane owns 4 channels (half4 = 8B gathers).
// 3-deep pipeline over 4-edge blocks: srcs t+3 | AL,h16 t+2 | compute t.
// mode 0: out[n,128] = ELU(acc/s + b)   mode 1: out[n,64] = mean_h(acc/s)+b
// ---------------------------------------------------------------------------
__global__ __launch_bounds__(256) void aggregate_kernel(
    const __half* __restrict__ H16, const float* __restrict__ AL,
    const int* __restrict__ dstptr, const int* __restrict__ ssrc,
    const unsigned* __restrict__ ubenc, const float* __restrict__ bias,
    float* __restrict__ out, int N, int mode)
{
    const int wid  = (blockIdx.x * blockDim.x + threadIdx.x) >> 6;
    const int lane = threadIdx.x & 63;
    if (wid * 2 >= N) return;
    const int nl   = lane & 31;               // lane within node
    const int n    = wid * 2 + (lane >> 5);
    const bool act = (n < N);
    const int nn   = act ? n : (N - 1);
    const int beg  = dstptr[nn];
    const int end  = act ? dstptr[nn + 1] : beg;

    const int head = nl >> 4;
    const float ald = AL[(size_t)nn * 4 + 2 + head];
    float ub = dec_max(ubenc[head]) + ald;
    ub = (ub >= 0.f) ? ub : NEG_SLOPE * ub;

    const int nblk = (end - beg + 3) >> 2;
    const int trips = max(nblk, __shfl_xor(nblk, 32, 64));

    float s = 0.f, a0 = 0.f, a1 = 0.f, a2 = 0.f, a3 = 0.f;

    int sA[4];
    float e0[4], e1[4];
    uint2 g0[4], g1[4];

    auto LSRC = [&](int b, int (&sv)[4]) {
#pragma unroll
        for (int k = 0; k < 4; k++) {
            const int idx = beg + 4 * b + k;
            const int v = ssrc[idx];            // padded: safe
            sv[k] = (idx < end) ? v : -1;       // -1 marks masked
        }
    };
    auto LHE = [&](const int (&sv)[4], float (&e)[4], uint2 (&g)[4]) {
#pragma unroll
        for (int k = 0; k < 4; k++) {
            const int src = (sv[k] >= 0) ? sv[k] : 0;
            const float a = AL[(size_t)src * 4 + head];
            e[k] = (sv[k] >= 0) ? a : -__builtin_inff();
            g[k] = ((const uint2*)(H16 + (size_t)src * 128))[nl];
        }
    };

    {   // prologue
        int ta[4], tb[4];
        LSRC(0, ta); LSRC(1, tb); LSRC(2, sA);
        LHE(ta, e0, g0);
        LHE(tb, e1, g1);
    }

    for (int t = 0; t < trips; t++) {
        int sB[4];
        LSRC(t + 3, sB);
        float e2[4]; uint2 g2[4];
        LHE(sA, e2, g2);
#pragma unroll
        for (int k = 0; k < 4; k++) {
            float tt = e0[k] + ald;
            tt = (tt >= 0.f) ? tt : NEG_SLOPE * tt;
            const float p = __expf(tt - ub);    // 0 for masked
            s += p;
            const __half2* ph = (const __half2*)&g0[k];
            const float2 f01 = __half22float2(ph[0]);
            const float2 f23 = __half22float2(ph[1]);
            a0 = fmaf(p, f01.x, a0);
            a1 = fmaf(p, f01.y, a1);
            a2 = fmaf(p, f23.x, a2);
            a3 = fmaf(p, f23.y, a3);
        }
#pragma unroll
        for (int k = 0; k < 4; k++) {
            e0[k] = e1[k]; g0[k] = g1[k];
            e1[k] = e2[k]; g1[k] = g2[k];
            sA[k] = sB[k];
        }
    }

    if (!act) return;
    const float inv = 1.f / s;                  // s > 0 (self loop)
    float o0 = a0 * inv, o1 = a1 * inv, o2 = a2 * inv, o3 = a3 * inv;

    if (mode == 0) {
        const float4 b4 = ((const float4*)bias)[nl];
        o0 += b4.x; o1 += b4.y; o2 += b4.z; o3 += b4.w;
        o0 = (o0 > 0.f) ? o0 : (__expf(o0) - 1.f);
        o1 = (o1 > 0.f) ? o1 : (__expf(o1) - 1.f);
        o2 = (o2 > 0.f) ? o2 : (__expf(o2) - 1.f);
        o3 = (o3 > 0.f) ? o3 : (__expf(o3) - 1.f);
        ((float4*)out)[(size_t)n * 32 + nl] = make_float4(o0, o1, o2, o3);
    } else {
        const float q0 = __shfl_xor(o0, 16, 64);   // swap heads within node
        const float q1 = __shfl_xor(o1, 16, 64);
        const float q2 = __shfl_xor(o2, 16, 64);
        const float q3 = __shfl_xor(o3, 16, 64);
        if (nl < 16) {
            const float4 b4 = ((const float4*)bias)[nl];
            ((float4*)out)[(size_t)n * 16 + nl] =
                make_float4(0.5f * (o0 + q0) + b4.x, 0.5f * (o1 + q1) + b4.y,
                            0.5f * (o2 + q2) + b4.z, 0.5f * (o3 + q3) + b4.w);
        }
    }
}

// ---------------------------------------------------------------------------
extern "C" void kernel_launch(void* const* d_in, const int* in_sizes, int n_in,
                              void* d_out, int out_size, void* d_ws, size_t ws_size,
                              hipStream_t stream)
{
    const float* x   = (const float*)d_in[0];
    const int*   eix = (const int*)d_in[1];   // [2, E] int32
    const float* W1  = (const float*)d_in[2];
    const float* as1 = (const float*)d_in[3];
    const float* ad1 = (const float*)d_in[4];
    const float* b1  = (const float*)d_in[5];
    const float* W2  = (const float*)d_in[6];
    const float* as2 = (const float*)d_in[7];
    const float* ad2 = (const float*)d_in[8];
    const float* b2  = (const float*)d_in[9];
    float* out = (float*)d_out;

    const int N = in_sizes[0] / 128;
    const int E = in_sizes[1] / 2;
    const int Etot = E + N;
    const int* esrc = eix;
    const int* edst = eix + E;

    // ---- workspace layout (~87 MB) ----
    char* p = (char*)d_ws;
    __half*   h16    = (__half*)p;   p += (size_t)N * 128 * 2;
    float*    y1     = (float*)p;    p += (size_t)N * 128 * 4;
    float*    al     = (float*)p;    p += (size_t)N * 4 * 4;
    int*      cnt    = (int*)p;      p += (size_t)N * 4;
    unsigned* ub     = (unsigned*)p; p += 64;                 // [0..1] L1, [2..3] L2
    int*      incl   = (int*)p;      p += (size_t)N * 4;
    int*      dstptr = (int*)p;      p += (size_t)(N + 1) * 4;
    int*      cursor = (int*)p;      p += (size_t)N * 4;
    int*      bs1    = (int*)p;      p += 1024 * 4;
    int*      ssrc   = (int*)p;      p += (size_t)(Etot + 256) * 4;  // pipeline pad

    hipMemsetAsync(cnt, 0, (size_t)N * 4 + 64, stream);   // cnt + ub

    // ---- CSR by destination (shared by both layers) ----
    {
        const int eblocks = (Etot + 255) / 256;
        const int B0 = (N + 1023) / 1024;
        count_kernel<<<eblocks, 256, 0, stream>>>(edst, cnt, E, N);
        scan_local_kernel<<<B0, 1024, 0, stream>>>(cnt, incl, bs1, N);
        scan_excl_single_kernel<<<1, 1024, 0, stream>>>(bs1, B0);
        finalize_csr_kernel<<<(N + 1024) / 1024, 1024, 0, stream>>>(
            incl, cnt, bs1, dstptr, cursor, N, Etot);
        const int sliceN = (N + 7) / 8;
        const int bps = 512;
        scatter_kernel<<<bps * 8, 256, 0, stream>>>(esrc, edst, cursor, ssrc,
                                                    E, N, sliceN, bps);
    }

    const int ggrid = (N + 127) / 128;                 // 128 rows/block
    const int nwaves = (N + 1) / 2;                    // 2 nodes/wave
    const int ablocks = (nwaves + 3) / 4;

    // ---- Layer 1 ----
    gemm_al_kernel<<<ggrid, 512, 0, stream>>>(x, W1, as1, ad1, h16, al, ub, N);
    aggregate_kernel<<<ablocks, 256, 0, stream>>>(h16, al, dstptr, ssrc, ub, b1, y1, N, 0);

    // ---- Layer 2 ----
    gemm_al_kernel<<<ggrid, 512, 0, stream>>>(y1, W2, as2, ad2, h16, al, ub + 2, N);
    aggregate_kernel<<<ablocks, 256, 0, stream>>>(h16, al, dstptr, ssrc, ub + 2, b2, out, N, 1);
}

// Round 7
// 377.022 us; speedup vs baseline: 1.2188x; 1.2188x over previous
//
#include <hip/hip_runtime.h>
#include <hip/hip_fp16.h>

#define NEG_SLOPE 0.2f

typedef _Float16 half4v __attribute__((ext_vector_type(4)));
typedef _Float16 half8v __attribute__((ext_vector_type(8)));
typedef float f32x4 __attribute__((ext_vector_type(4)));

// ---------------------------------------------------------------------------
// float<->ordered-uint encoding for atomicMax on floats
// ---------------------------------------------------------------------------
__device__ inline unsigned enc_max(float f) {
    unsigned b = __float_as_uint(f);
    return (b & 0x80000000u) ? ~b : (b | 0x80000000u);
}
__device__ inline float dec_max(unsigned k) {
    return (k & 0x80000000u) ? __uint_as_float(k ^ 0x80000000u)
                             : __uint_as_float(~k);
}

// ---------------------------------------------------------------------------
// MFMA GEMM + attention projections.
//   H16[r,:] = fp16(X[r,:] @ W); AL[r] = (als_h0, als_h1, ald_h0, ald_h1)
// Block = 256 thr = 4 waves, 64 rows. X and W^T staged as fp16 in LDS with a
// (k8 ^ row&7) 16B-slot XOR swizzle (conflict-free frag reads). Each wave:
// one 16-row tile, 8 col-tiles, 8 K-steps of v_mfma_f32_16x16x16f16.
// Fragment layout (classic CDNA): A: row=l&15, k=4*(l>>4)+j; B: col=l&15,
// same k; D: col=l&15, row=(l>>4)*4+reg  [m89-verified].
// Epilogue: AL + ub from f32 accs in-register; D -> LDS (reuse staging after
// sync, row stride 132 f32) -> coalesced fp16 global write.
// LDS = 48 KB. Also folds global max of als per head (ub) via 2 atomics.
// ---------------------------------------------------------------------------
__global__ __launch_bounds__(256) void gemm_al_kernel(
    const float* __restrict__ X, const float* __restrict__ W,
    const float* __restrict__ asrc, const float* __restrict__ adst,
    __half* __restrict__ H16, float* __restrict__ AL,
    unsigned* __restrict__ ubp, int N)
{
    __shared__ alignas(16) char smem[49152];
    // Xl: bytes [0, 16384): 64 rows x 16 slots of 16B (8 f16), swizzled
    // Wt: bytes [16384, 49152): 128 cols x 16 slots of 16B, swizzled
    // D (after sync): floats [0, 8448*4): 4 waves x 16 rows x 132 f32
    // red: bytes [33792, 33824): 8 floats (per-wave ub partials)

    const int t = threadIdx.x, lane = t & 63, wave = t >> 6;
    const int r0 = blockIdx.x * 64;

    // ---- stage X (fp32 -> fp16, swizzled 16B slots) ----
#pragma unroll
    for (int i = 0; i < 8; i++) {
        const int f = t + i * 256;            // 2048 float4 chunks
        const int row = f >> 5, k4 = f & 31;  // k4 = float4 index in row
        const int k8 = k4 >> 1, hf = k4 & 1;
        float4 v = make_float4(0.f, 0.f, 0.f, 0.f);
        if (r0 + row < N) v = ((const float4*)X)[(size_t)(r0 + row) * 32 + k4];
        half4v h = { (_Float16)v.x, (_Float16)v.y, (_Float16)v.z, (_Float16)v.w };
        const int slot = row * 16 + (k8 ^ (row & 7));
        *(half4v*)(smem + slot * 16 + hf * 8) = h;
    }
    // ---- stage W^T (fp32 -> fp16, swizzled) ----
    {
        const int c = t >> 1, kh = t & 1;
        const float* Wc = W + c;              // W[k][c], stride 128
#pragma unroll
        for (int i8 = 0; i8 < 8; i8++) {
            const int k0 = kh * 64 + i8 * 8;
            half8v h;
#pragma unroll
            for (int j = 0; j < 8; j++) h[j] = (_Float16)Wc[(size_t)(k0 + j) * 128];
            const int slot = c * 16 + ((k0 >> 3) ^ (c & 7));
            *(half8v*)(smem + 16384 + slot * 16) = h;
        }
    }
    __syncthreads();

    // ---- MFMA ----
    const int mrow = wave * 16 + (lane & 15);   // local row for A
    const int kg = lane >> 4;                   // k-group 0..3
    half4v a[8];
#pragma unroll
    for (int ks = 0; ks < 8; ks++) {
        const int k0 = ks * 16 + kg * 4;
        const int slot = mrow * 16 + ((k0 >> 3) ^ (mrow & 7));
        a[ks] = *(const half4v*)(smem + slot * 16 + (k0 & 7) * 2);
    }
    f32x4 acc[8];
#pragma unroll
    for (int ct = 0; ct < 8; ct++) acc[ct] = (f32x4){0.f, 0.f, 0.f, 0.f};
#pragma unroll
    for (int ct = 0; ct < 8; ct++) {
        const int c = ct * 16 + (lane & 15);
        const char* sbase = smem + 16384 + c * 256;
        const int csw = c & 7;
#pragma unroll
        for (int ks = 0; ks < 8; ks++) {
            const int k0 = ks * 16 + kg * 4;
            const int slot = (k0 >> 3) ^ csw;
            half4v b = *(const half4v*)(sbase + slot * 16 + (k0 & 7) * 2);
            acc[ct] = __builtin_amdgcn_mfma_f32_16x16x16f16(a[ks], b, acc[ct], 0, 0, 0);
        }
    }

    // ---- AL projections + per-head max (from exact f32 accumulators) ----
    float psh0[4] = {0,0,0,0}, psh1[4] = {0,0,0,0};
    float pdh0[4] = {0,0,0,0}, pdh1[4] = {0,0,0,0};
#pragma unroll
    for (int ct = 0; ct < 8; ct++) {
        const int c = ct * 16 + (lane & 15);
        const float as = asrc[c], ad = adst[c];
#pragma unroll
        for (int r = 0; r < 4; r++) {
            if (ct < 4) { psh0[r] = fmaf(acc[ct][r], as, psh0[r]);
                          pdh0[r] = fmaf(acc[ct][r], ad, pdh0[r]); }
            else        { psh1[r] = fmaf(acc[ct][r], as, psh1[r]);
                          pdh1[r] = fmaf(acc[ct][r], ad, pdh1[r]); }
        }
    }
#pragma unroll
    for (int off = 1; off <= 8; off <<= 1) {
#pragma unroll
        for (int r = 0; r < 4; r++) {
            psh0[r] += __shfl_xor(psh0[r], off, 64);
            psh1[r] += __shfl_xor(psh1[r], off, 64);
            pdh0[r] += __shfl_xor(pdh0[r], off, 64);
            pdh1[r] += __shfl_xor(pdh1[r], off, 64);
        }
    }
    float rmax0 = -__builtin_inff(), rmax1 = -__builtin_inff();
    if ((lane & 15) == 0) {
#pragma unroll
        for (int r = 0; r < 4; r++) {
            const int gr = r0 + wave * 16 + (lane >> 4) * 4 + r;
            if (gr < N) {
                ((float4*)AL)[gr] = make_float4(psh0[r], psh1[r], pdh0[r], pdh1[r]);
                rmax0 = fmaxf(rmax0, psh0[r]);
                rmax1 = fmaxf(rmax1, psh1[r]);
            }
        }
    }
#pragma unroll
    for (int off = 32; off > 0; off >>= 1) {
        rmax0 = fmaxf(rmax0, __shfl_xor(rmax0, off, 64));
        rmax1 = fmaxf(rmax1, __shfl_xor(rmax1, off, 64));
    }

    // ---- D -> LDS (reuse staging), then coalesced fp16 write ----
    __syncthreads();                       // all frag reads of Xl/Wt done
    float* Dst = (float*)smem;
    float* red = (float*)(smem + 33792);
    if (lane == 0) { red[wave * 2] = rmax0; red[wave * 2 + 1] = rmax1; }
#pragma unroll
    for (int ct = 0; ct < 8; ct++) {
        const int col = ct * 16 + (lane & 15);
        float* drow = Dst + wave * 2112 + ((lane >> 4) * 4) * 132 + col;
#pragma unroll
        for (int r = 0; r < 4; r++) drow[r * 132] = acc[ct][r];
    }
    __syncthreads();
    if (t < 2) {
        float m = fmaxf(fmaxf(red[t], red[2 + t]), fmaxf(red[4 + t], red[6 + t]));
        atomicMax(&ubp[t], enc_max(m));
    }
#pragma unroll
    for (int i = 0; i < 4; i++) {
        const int f = t + i * 256;            // 1024 chunks of 8 cols
        const int row = f >> 4, c16 = f & 15;
        if (r0 + row < N) {
            const float* src = Dst + (row >> 4) * 2112 + (row & 15) * 132 + c16 * 8;
            const float4 v0 = *(const float4*)src;
            const float4 v1 = *(const float4*)(src + 4);
            half8v h = { (_Float16)v0.x, (_Float16)v0.y, (_Float16)v0.z, (_Float16)v0.w,
                         (_Float16)v1.x, (_Float16)v1.y, (_Float16)v1.z, (_Float16)v1.w };
            *(half8v*)((_Float16*)H16 + (size_t)(r0 + row) * 128 + c16 * 8) = h;
        }
    }
}

// ---------------------------------------------------------------------------
// Plain per-dst CSR build (count -> scan -> sliced scatter). Self-loops added.
// ---------------------------------------------------------------------------
__global__ void count_kernel(const int* __restrict__ edst, int* __restrict__ cnt,
                             int E, int N)
{
    int i = blockIdx.x * 256 + threadIdx.x;
    if (i < E)            atomicAdd(&cnt[edst[i]], 1);
    else if (i < E + N)   atomicAdd(&cnt[i - E], 1);   // self loop
}

__global__ void scan_local_kernel(const int* __restrict__ in, int* __restrict__ out,
                                  int* __restrict__ bsum, int n)
{
    __shared__ int sm[1024];
    const int t = threadIdx.x;
    const int i = blockIdx.x * 1024 + t;
    int v = (i < n) ? in[i] : 0;
    sm[t] = v;
    __syncthreads();
    for (int off = 1; off < 1024; off <<= 1) {
        int x = (t >= off) ? sm[t - off] : 0;
        __syncthreads();
        sm[t] += x;
        __syncthreads();
    }
    if (i < n) out[i] = sm[t];
    if (t == 1023) bsum[blockIdx.x] = sm[t];
}

__global__ void scan_excl_single_kernel(int* __restrict__ a, int B)
{
    __shared__ int sm[1024];
    const int t = threadIdx.x;
    int v = (t < B) ? a[t] : 0;
    sm[t] = v;
    __syncthreads();
    for (int off = 1; off < 1024; off <<= 1) {
        int x = (t >= off) ? sm[t - off] : 0;
        __syncthreads();
        sm[t] += x;
        __syncthreads();
    }
    if (t < B) a[t] = sm[t] - v;   // exclusive
}

__global__ void finalize_csr_kernel(const int* __restrict__ incl,
                                    const int* __restrict__ cnt,
                                    const int* __restrict__ bexcl,
                                    int* __restrict__ dstptr, int* __restrict__ cursor,
                                    int N, int Etot)
{
    const int i = blockIdx.x * 1024 + threadIdx.x;
    if (i < N) {
        int v = incl[i] + bexcl[i >> 10] - cnt[i];
        dstptr[i] = v;
        cursor[i] = v;
    }
    if (i == N) dstptr[N] = Etot;
}

// Sliced scatter: blocks with blockIdx%8==s handle dst slice s (-> one XCD by
// round-robin dispatch), so each ssrc cache line is written by one XCD only.
__global__ void scatter_kernel(const int* __restrict__ esrc, const int* __restrict__ edst,
                               int* __restrict__ cursor, int* __restrict__ ssrc,
                               int E, int N, int sliceN, int bps)
{
    const int slice = blockIdx.x & 7;
    const int dlo = slice * sliceN;
    const int dhi = min(N, dlo + sliceN);
    const int Etot = E + N;
    for (int i = (blockIdx.x >> 3) * 256 + (int)threadIdx.x; i < Etot; i += bps * 256) {
        int s, d;
        if (i < E) { s = esrc[i]; d = edst[i]; }
        else       { s = d = i - E; }
        if (d >= dlo && d < dhi) {
            int pos = atomicAdd(&cursor[d], 1);
            ssrc[pos] = s;
        }
    }
}

// ---------------------------------------------------------------------------
// Aggregation, shifted softmax. TWO nodes per wave: lanes 0-31 node A,
// lanes 32-63 node B; lane owns 4 channels (half4 = 8B gathers).
// 3-deep pipeline over 4-edge blocks: srcs t+3 | AL,h16 t+2 | compute t.
// mode 0: out[n,128] = ELU(acc/s + b)   mode 1: out[n,64] = mean_h(acc/s)+b
// ---------------------------------------------------------------------------
__global__ __launch_bounds__(256) void aggregate_kernel(
    const __half* __restrict__ H16, const float* __restrict__ AL,
    const int* __restrict__ dstptr, const int* __restrict__ ssrc,
    const unsigned* __restrict__ ubenc, const float* __restrict__ bias,
    float* __restrict__ out, int N, int mode)
{
    const int wid  = (blockIdx.x * blockDim.x + threadIdx.x) >> 6;
    const int lane = threadIdx.x & 63;
    if (wid * 2 >= N) return;
    const int nl   = lane & 31;               // lane within node
    const int n    = wid * 2 + (lane >> 5);
    const bool act = (n < N);
    const int nn   = act ? n : (N - 1);
    const int beg  = dstptr[nn];
    const int end  = act ? dstptr[nn + 1] : beg;

    const int head = nl >> 4;
    const float ald = AL[(size_t)nn * 4 + 2 + head];
    float ub = dec_max(ubenc[head]) + ald;
    ub = (ub >= 0.f) ? ub : NEG_SLOPE * ub;

    const int nblk = (end - beg + 3) >> 2;
    const int trips = max(nblk, __shfl_xor(nblk, 32, 64));

    float s = 0.f, a0 = 0.f, a1 = 0.f, a2 = 0.f, a3 = 0.f;

    int sA[4];
    float e0[4], e1[4];
    uint2 g0[4], g1[4];

    auto LSRC = [&](int b, int (&sv)[4]) {
#pragma unroll
        for (int k = 0; k < 4; k++) {
            const int idx = beg + 4 * b + k;
            const int v = ssrc[idx];            // padded: safe
            sv[k] = (idx < end) ? v : -1;       // -1 marks masked
        }
    };
    auto LHE = [&](const int (&sv)[4], float (&e)[4], uint2 (&g)[4]) {
#pragma unroll
        for (int k = 0; k < 4; k++) {
            const int src = (sv[k] >= 0) ? sv[k] : 0;
            const float a = AL[(size_t)src * 4 + head];
            e[k] = (sv[k] >= 0) ? a : -__builtin_inff();
            g[k] = ((const uint2*)(H16 + (size_t)src * 128))[nl];
        }
    };

    {   // prologue
        int ta[4], tb[4];
        LSRC(0, ta); LSRC(1, tb); LSRC(2, sA);
        LHE(ta, e0, g0);
        LHE(tb, e1, g1);
    }

    for (int t = 0; t < trips; t++) {
        int sB[4];
        LSRC(t + 3, sB);
        float e2[4]; uint2 g2[4];
        LHE(sA, e2, g2);
#pragma unroll
        for (int k = 0; k < 4; k++) {
            float tt = e0[k] + ald;
            tt = (tt >= 0.f) ? tt : NEG_SLOPE * tt;
            const float p = __expf(tt - ub);    // 0 for masked
            s += p;
            const __half2* ph = (const __half2*)&g0[k];
            const float2 f01 = __half22float2(ph[0]);
            const float2 f23 = __half22float2(ph[1]);
            a0 = fmaf(p, f01.x, a0);
            a1 = fmaf(p, f01.y, a1);
            a2 = fmaf(p, f23.x, a2);
            a3 = fmaf(p, f23.y, a3);
        }
#pragma unroll
        for (int k = 0; k < 4; k++) {
            e0[k] = e1[k]; g0[k] = g1[k];
            e1[k] = e2[k]; g1[k] = g2[k];
            sA[k] = sB[k];
        }
    }

    if (!act) return;
    const float inv = 1.f / s;                  // s > 0 (self loop)
    float o0 = a0 * inv, o1 = a1 * inv, o2 = a2 * inv, o3 = a3 * inv;

    if (mode == 0) {
        const float4 b4 = ((const float4*)bias)[nl];
        o0 += b4.x; o1 += b4.y; o2 += b4.z; o3 += b4.w;
        o0 = (o0 > 0.f) ? o0 : (__expf(o0) - 1.f);
        o1 = (o1 > 0.f) ? o1 : (__expf(o1) - 1.f);
        o2 = (o2 > 0.f) ? o2 : (__expf(o2) - 1.f);
        o3 = (o3 > 0.f) ? o3 : (__expf(o3) - 1.f);
        ((float4*)out)[(size_t)n * 32 + nl] = make_float4(o0, o1, o2, o3);
    } else {
        const float q0 = __shfl_xor(o0, 16, 64);   // swap heads within node
        const float q1 = __shfl_xor(o1, 16, 64);
        const float q2 = __shfl_xor(o2, 16, 64);
        const float q3 = __shfl_xor(o3, 16, 64);
        if (nl < 16) {
            const float4 b4 = ((const float4*)bias)[nl];
            ((float4*)out)[(size_t)n * 16 + nl] =
                make_float4(0.5f * (o0 + q0) + b4.x, 0.5f * (o1 + q1) + b4.y,
                            0.5f * (o2 + q2) + b4.z, 0.5f * (o3 + q3) + b4.w);
        }
    }
}

// ---------------------------------------------------------------------------
extern "C" void kernel_launch(void* const* d_in, const int* in_sizes, int n_in,
                              void* d_out, int out_size, void* d_ws, size_t ws_size,
                              hipStream_t stream)
{
    const float* x   = (const float*)d_in[0];
    const int*   eix = (const int*)d_in[1];   // [2, E] int32
    const float* W1  = (const float*)d_in[2];
    const float* as1 = (const float*)d_in[3];
    const float* ad1 = (const float*)d_in[4];
    const float* b1  = (const float*)d_in[5];
    const float* W2  = (const float*)d_in[6];
    const float* as2 = (const float*)d_in[7];
    const float* ad2 = (const float*)d_in[8];
    const float* b2  = (const float*)d_in[9];
    float* out = (float*)d_out;

    const int N = in_sizes[0] / 128;
    const int E = in_sizes[1] / 2;
    const int Etot = E + N;
    const int* esrc = eix;
    const int* edst = eix + E;

    // ---- workspace layout (~87 MB) ----
    char* p = (char*)d_ws;
    __half*   h16    = (__half*)p;   p += (size_t)N * 128 * 2;
    float*    y1     = (float*)p;    p += (size_t)N * 128 * 4;
    float*    al     = (float*)p;    p += (size_t)N * 4 * 4;
    int*      cnt    = (int*)p;      p += (size_t)N * 4;
    unsigned* ub     = (unsigned*)p; p += 64;                 // [0..1] L1, [2..3] L2
    int*      incl   = (int*)p;      p += (size_t)N * 4;
    int*      dstptr = (int*)p;      p += (size_t)(N + 1) * 4;
    int*      cursor = (int*)p;      p += (size_t)N * 4;
    int*      bs1    = (int*)p;      p += 1024 * 4;
    int*      ssrc   = (int*)p;      p += (size_t)(Etot + 256) * 4;  // pipeline pad

    hipMemsetAsync(cnt, 0, (size_t)N * 4 + 64, stream);   // cnt + ub

    // ---- CSR by destination (shared by both layers) ----
    {
        const int eblocks = (Etot + 255) / 256;
        const int B0 = (N + 1023) / 1024;
        count_kernel<<<eblocks, 256, 0, stream>>>(edst, cnt, E, N);
        scan_local_kernel<<<B0, 1024, 0, stream>>>(cnt, incl, bs1, N);
        scan_excl_single_kernel<<<1, 1024, 0, stream>>>(bs1, B0);
        finalize_csr_kernel<<<(N + 1024) / 1024, 1024, 0, stream>>>(
            incl, cnt, bs1, dstptr, cursor, N, Etot);
        const int sliceN = (N + 7) / 8;
        const int bps = 512;
        scatter_kernel<<<bps * 8, 256, 0, stream>>>(esrc, edst, cursor, ssrc,
                                                    E, N, sliceN, bps);
    }

    const int ggrid = (N + 63) / 64;                   // 64 rows/block (MFMA)
    const int nwaves = (N + 1) / 2;                    // 2 nodes/wave
    const int ablocks = (nwaves + 3) / 4;

    // ---- Layer 1 ----
    gemm_al_kernel<<<ggrid, 256, 0, stream>>>(x, W1, as1, ad1, h16, al, ub, N);
    aggregate_kernel<<<ablocks, 256, 0, stream>>>(h16, al, dstptr, ssrc, ub, b1, y1, N, 0);

    // ---- Layer 2 ----
    gemm_al_kernel<<<ggrid, 256, 0, stream>>>(y1, W2, as2, ad2, h16, al, ub + 2, N);
    aggregate_kernel<<<ablocks, 256, 0, stream>>>(h16, al, dstptr, ssrc, ub + 2, b2, out, N, 1);
}